// Round 2
// baseline (876.631 us; speedup 1.0000x reference)
//
#include <hip/hip_runtime.h>
#include <hip/hip_bf16.h>
#include <stdint.h>

// out[b,o] = sum_i (bw[o,i] + dwb[o*IN+i] + sum_k z[b,k] dwW[o*IN+i,k]) x[b,i]
//            + bbias[o] + dbb[o] + sum_k z[b,k] dbW[o,k]
// All inputs/outputs fp32 (per reference). Big term rewritten as GEMM:
//   out_big[b,o] = sum_kk y[b,kk] * dwW[o,kk],  y[b, i*128+k] = x[b,i]*z[b,k]
// y is built on the fly in registers (never materialized); dwW [1024 x 131072]
// row-major = B^T GEMM (m97 pattern), fp32->bf16 converted during LDS staging.
// HBM floor = 512 MB (dwW once) / 6.3 TB/s ~ 81 us -> memory-bound.

#define IN_N  1024
#define OUT_N 1024
#define ZD_N  128
#define KK    (IN_N * ZD_N)   // 131072
#define KSPLIT 64
#define KSPAN  (KK / KSPLIT)  // 2048
#define BK     64
#define NCHUNK (KSPAN / BK)   // 32

typedef __attribute__((ext_vector_type(8))) short s16x8;  // 8 bf16 = 4 VGPRs
typedef __attribute__((ext_vector_type(4))) float f32x4;

union BF8 { s16x8 v; short4 h[2]; __hip_bfloat162 b[4]; };

// ---------------- small part: writes every out element (fp32) ---------------------------
__global__ __launch_bounds__(256) void init_small(
    const float* __restrict__ x, const float* __restrict__ z,
    const float* __restrict__ bw, const float* __restrict__ dwb,
    const float* __restrict__ bbias, const float* __restrict__ dbW,
    const float* __restrict__ dbb, float* __restrict__ out)
{
    const int tid = threadIdx.x;
    const int b   = tid & 127;
    const int oh  = tid >> 7;                 // wave-uniform
    const int o0  = blockIdx.x * 4 + oh * 2;  // 2 outputs per thread

    float acc0 = bbias[o0]     + dbb[o0];
    float acc1 = bbias[o0 + 1] + dbb[o0 + 1];

    // delta_b = z @ dbW^T
    const float* zrow = z + (size_t)b * ZD_N;
    for (int k = 0; k < ZD_N; k += 4) {
        float4 zv = *(const float4*)(zrow + k);
        float4 d0 = *(const float4*)(dbW + (size_t)o0 * ZD_N + k);
        float4 d1 = *(const float4*)(dbW + (size_t)(o0 + 1) * ZD_N + k);
        acc0 += zv.x * d0.x + zv.y * d0.y + zv.z * d0.z + zv.w * d0.w;
        acc1 += zv.x * d1.x + zv.y * d1.y + zv.z * d1.z + zv.w * d1.w;
    }
    // x @ (bw + dwb_view)^T  (fp32 exact)
    const float* xrow = x + (size_t)b * IN_N;
    for (int i = 0; i < IN_N; i += 4) {
        float4 xv = *(const float4*)(xrow + i);
        float4 w0 = *(const float4*)(bw  + (size_t)o0 * IN_N + i);
        float4 v0 = *(const float4*)(dwb + (size_t)o0 * IN_N + i);
        float4 w1 = *(const float4*)(bw  + (size_t)(o0 + 1) * IN_N + i);
        float4 v1 = *(const float4*)(dwb + (size_t)(o0 + 1) * IN_N + i);
        acc0 += xv.x * (w0.x + v0.x) + xv.y * (w0.y + v0.y)
              + xv.z * (w0.z + v0.z) + xv.w * (w0.w + v0.w);
        acc1 += xv.x * (w1.x + v1.x) + xv.y * (w1.y + v1.y)
              + xv.z * (w1.z + v1.z) + xv.w * (w1.w + v1.w);
    }
    out[(size_t)b * OUT_N + o0]     = acc0;
    out[(size_t)b * OUT_N + o0 + 1] = acc1;
}

// ---------------- big GEMM: split-K, on-the-fly A = x (x) z, atomic fp32 accumulate ------
__global__ __launch_bounds__(256, 2) void hyper_gemm(
    const float* __restrict__ x,    // [128,1024] fp32
    const float* __restrict__ z,    // [128,128]  fp32
    const float* __restrict__ dwW,  // [1024,131072] fp32 row-major
    float* __restrict__ out)        // [128,1024] fp32 (pre-initialized by init_small)
{
    // B-tile LDS (bf16): granule (8 along kk) layout [g 0..7][n^g 0..127], XOR swizzle.
    __shared__ s16x8 blds[2][8 * 128];

    const int tid  = threadIdx.x;
    const int lane = tid & 63;
    const int w    = tid >> 6;
    const int wm   = (w & 1) * 64;   // wave 2x2 over the 128x128 tile
    const int wn   = (w >> 1) * 64;
    const int q    = lane >> 4;
    const int l16  = lane & 15;

    const int nb = blockIdx.x & 7;        // 8 n-tiles
    const int ks = blockIdx.x >> 3;       // 64 k-splits
    const int n0 = nb * 128;
    const long long kk0 = (long long)ks * KSPAN;

    f32x4 acc[4][4];
#pragma unroll
    for (int mt = 0; mt < 4; ++mt)
#pragma unroll
        for (int nt = 0; nt < 4; ++nt) acc[mt][nt] = (f32x4)0.0f;

    // Per-thread staging geometry: 16 lanes cover one 64-float (256 B) row segment.
    const int q4   = tid & 15;   // which float4 within the 64-kk segment
    const int nrow = tid >> 4;   // base row
    const int gst  = q4 >> 1;    // LDS granule (8 bf16)
    const int hst  = q4 & 1;     // which half (short4) of the granule

    float4 breg[8];
#define LOAD_B(c)                                                                   \
    {                                                                               \
        _Pragma("unroll") for (int j = 0; j < 8; ++j) {                             \
            int n = j * 16 + nrow;                                                  \
            breg[j] = *(const float4*)(dwW + (size_t)(n0 + n) * KK +                \
                                       (size_t)(kk0 + (c) * BK + q4 * 4));          \
        }                                                                           \
    }

    LOAD_B(0);

    for (int c = 0; c < NCHUNK; ++c) {
        // convert fp32 -> bf16, stage into buf[c&1]
#pragma unroll
        for (int j = 0; j < 8; ++j) {
            int n = j * 16 + nrow;
            union { short4 s; __hip_bfloat162 b[2]; } u;
            u.b[0] = __float22bfloat162_rn(make_float2(breg[j].x, breg[j].y));
            u.b[1] = __float22bfloat162_rn(make_float2(breg[j].z, breg[j].w));
            ((short4*)&blds[c & 1][gst * 128 + (n ^ gst)])[hst] = u.s;
        }
        __syncthreads();
        if (c + 1 < NCHUNK) LOAD_B(c + 1);  // prefetch overlaps compute

        const long long kkb = kk0 + (long long)c * BK;
        const int i_c = (int)(kkb >> 7);        // x column (constant within chunk)
        const int kzb = (int)(kkb & 127);       // z base: 0 or 64
        const s16x8* bufp = &blds[c & 1][0];

#pragma unroll
        for (int s = 0; s < 2; ++s) {           // two K=32 MFMA steps
            const int gq = s * 4 + q;
            s16x8 bfr[4];
#pragma unroll
            for (int nt = 0; nt < 4; ++nt) {
                int nl = wn + nt * 16 + l16;
                bfr[nt] = bufp[gq * 128 + (nl ^ gq)];
            }
#pragma unroll
            for (int mt = 0; mt < 4; ++mt) {
                const int m = wm + mt * 16 + l16;
                const float xv = x[(size_t)m * IN_N + i_c];
                const float* zp = z + (size_t)m * ZD_N + kzb + s * 32 + q * 8;
                float4 z0 = *(const float4*)(zp);
                float4 z1 = *(const float4*)(zp + 4);
                BF8 af;
                af.b[0] = __float22bfloat162_rn(make_float2(xv * z0.x, xv * z0.y));
                af.b[1] = __float22bfloat162_rn(make_float2(xv * z0.z, xv * z0.w));
                af.b[2] = __float22bfloat162_rn(make_float2(xv * z1.x, xv * z1.y));
                af.b[3] = __float22bfloat162_rn(make_float2(xv * z1.z, xv * z1.w));
#pragma unroll
                for (int nt = 0; nt < 4; ++nt)
                    acc[mt][nt] = __builtin_amdgcn_mfma_f32_16x16x32_bf16(
                        af.v, bfr[nt], acc[mt][nt], 0, 0, 0);
            }
        }
        __syncthreads();
    }

    // epilogue: C/D layout col=lane&15 (=n), row=(lane>>4)*4+r (=m)
#pragma unroll
    for (int mt = 0; mt < 4; ++mt) {
        const int mbase = wm + mt * 16 + q * 4;
#pragma unroll
        for (int nt = 0; nt < 4; ++nt) {
            const int o = n0 + wn + nt * 16 + l16;
#pragma unroll
            for (int r = 0; r < 4; ++r)
                atomicAdd(&out[(size_t)(mbase + r) * OUT_N + o], acc[mt][nt][r]);
        }
    }
#undef LOAD_B
}

extern "C" void kernel_launch(void* const* d_in, const int* in_sizes, int n_in,
                              void* d_out, int out_size, void* d_ws, size_t ws_size,
                              hipStream_t stream) {
    const float* x     = (const float*)d_in[0];
    const float* z     = (const float*)d_in[1];
    const float* bw    = (const float*)d_in[2];
    const float* dwW   = (const float*)d_in[3];
    const float* dwb   = (const float*)d_in[4];
    const float* bbias = (const float*)d_in[5];
    const float* dbW   = (const float*)d_in[6];
    const float* dbb   = (const float*)d_in[7];
    float* out = (float*)d_out;

    hipLaunchKernelGGL(init_small, dim3(256), dim3(256), 0, stream,
                       x, z, bw, dwb, bbias, dbW, dbb, out);
    hipLaunchKernelGGL(hyper_gemm, dim3(512), dim3(256), 0, stream, x, z, dwW, out);
}